// Round 2
// baseline (237.071 us; speedup 1.0000x reference)
//
#include <hip/hip_runtime.h>

// Depthwise Conv1d: B=32, C=128, L=8192, K=3, pad=1, fp32.
// out[b,c,l] = w[c,0]*x[b,c,l-1] + w[c,1]*x[b,c,l] + w[c,2]*x[b,c,l+1] + bias[c]
// Memory-bound: ideal traffic 128 MiB read + 128 MiB write → ~43 µs @ 6.3 TB/s.
//
// Layout exploit: L4 = 2048 float4 per row, so a 64-lane wave never spans a
// row boundary (2048 % 64 == 0) → channel is wave-uniform (weights via s_load),
// halo from neighbor lanes via shuffle; only lanes 0/63 do an exec-masked
// scalar load (2 per wave-iteration).
//
// Persistent grid-stride: GRID=2048 (8 blocks/CU × 256 CUs, 32 waves/CU),
// STRIDE = 524288 float4 = exactly 256 rows → channel index (idx>>11)&127 and
// in-row position idx&2047 are ITERATION-INVARIANT: weights/bias/edge
// predicates hoisted out of the loop entirely. Loads batched 4-deep for MLP.

constexpr int C  = 128;
constexpr int L  = 8192;
constexpr int L4 = L / 4;          // 2048 float4 per row
constexpr int B  = 32;
constexpr int TOTAL4 = B * C * L4; // 8,388,608

constexpr int BLOCK  = 256;
constexpr int GRID   = 2048;             // 8 blocks/CU
constexpr int STRIDE = BLOCK * GRID;     // 524,288 float4 = 256 rows
constexpr int ITER   = TOTAL4 / STRIDE;  // 16, exact
constexpr int BATCH  = 4;                // loads in flight per thread

static_assert(TOTAL4 % STRIDE == 0, "exact tiling");
static_assert((STRIDE / L4) % C == 0, "channel invariant across iterations");

// Native clang vector type — __builtin_nontemporal_store rejects
// HIP_vector_type<float,4>; this is bit-identical and still one dwordx4.
typedef float floatx4 __attribute__((ext_vector_type(4)));

__global__ __launch_bounds__(BLOCK) void dwconv1d_kernel(
    const float4* __restrict__ x4,
    const float* __restrict__ x,      // scalar view of same buffer (edge halos)
    const float* __restrict__ w,      // [C,3]
    const float* __restrict__ bias,   // [C]
    float4* __restrict__ out4)
{
    const int idx0 = blockIdx.x * BLOCK + threadIdx.x;
    const int lane = threadIdx.x & 63;
    const int i4   = idx0 & (L4 - 1);   // invariant across iterations

    // Channel is identical across the wave -> force scalar (s_load) path.
    const int c = __builtin_amdgcn_readfirstlane((idx0 >> 11) & (C - 1));
    const float w0 = w[c * 3 + 0];
    const float w1 = w[c * 3 + 1];
    const float w2 = w[c * 3 + 2];
    const float bc = bias[c];

    // Edge predicates — invariant across iterations.
    const bool lane0    = (lane == 0);
    const bool lane63   = (lane == 63);
    const bool rowstart = (i4 == 0);        // implies lane==0
    const bool rowend   = (i4 == L4 - 1);   // implies lane==63

    #pragma unroll
    for (int jo = 0; jo < ITER / BATCH; ++jo) {
        int    idx[BATCH];
        float4 v[BATCH];

        // Issue all BATCH loads before any use → 4 outstanding dwordx4.
        #pragma unroll
        for (int ji = 0; ji < BATCH; ++ji) {
            idx[ji] = idx0 + (jo * BATCH + ji) * STRIDE;
            v[ji]   = x4[idx[ji]];
        }

        #pragma unroll
        for (int ji = 0; ji < BATCH; ++ji) {
            const float4 vv = v[ji];

            // Halo from neighbor lanes (wave = 64 lanes on CDNA).
            float left  = __shfl_up(vv.w, 1);   // lane i gets lane i-1's v.w
            float right = __shfl_down(vv.x, 1); // lane i gets lane i+1's v.x

            // Wave-edge lanes fetch across the wave boundary (or 0 at row edges).
            const long base = (long)idx[ji] * 4;
            if (lane0)  left  = rowstart ? 0.0f : x[base - 1];
            if (lane63) right = rowend   ? 0.0f : x[base + 4];

            floatx4 o;
            o.x = fmaf(w0, left,  fmaf(w1, vv.x, fmaf(w2, vv.y, bc)));
            o.y = fmaf(w0, vv.x,  fmaf(w1, vv.y, fmaf(w2, vv.z, bc)));
            o.z = fmaf(w0, vv.y,  fmaf(w1, vv.z, fmaf(w2, vv.w, bc)));
            o.w = fmaf(w0, vv.z,  fmaf(w1, vv.w, fmaf(w2, right, bc)));

            // Pure streaming output — never re-read; keep it out of L2/L3.
            __builtin_nontemporal_store(o, (floatx4*)&out4[idx[ji]]);
        }
    }
}

extern "C" void kernel_launch(void* const* d_in, const int* in_sizes, int n_in,
                              void* d_out, int out_size, void* d_ws, size_t ws_size,
                              hipStream_t stream)
{
    const float* x    = (const float*)d_in[0];  // [B,C,L]
    const float* w    = (const float*)d_in[1];  // [C,3]
    const float* bias = (const float*)d_in[2];  // [C]
    float* out        = (float*)d_out;

    dwconv1d_kernel<<<GRID, BLOCK, 0, stream>>>(
        (const float4*)x, x, w, bias, (float4*)out);
}

// Round 3
// 233.108 us; speedup vs baseline: 1.0170x; 1.0170x over previous
//
#include <hip/hip_runtime.h>

// Depthwise Conv1d: B=32, C=128, L=8192, K=3, pad=1, fp32.
// out[b,c,l] = w[c,0]*x[b,c,l-1] + w[c,1]*x[b,c,l] + w[c,2]*x[b,c,l+1] + bias[c]
// Memory-bound: ideal traffic 128 MiB read + 128 MiB write → ~43 µs @ 6.3 TB/s.
//
// Layout exploit: L4 = 2048 float4 per row, so a 64-lane wave never spans a
// row boundary (2048 % 64 == 0) → channel is wave-uniform (weights via s_load),
// halo from neighbor lanes via shuffle; only lanes 0/63 do an exec-masked
// scalar load (2 per wave-item).
//
// R2 post-mortem: persistent grid (2048 blocks × 16 items) + nontemporal
// stores REGRESSED conv 65→81 µs (2.6 TB/s): nt bypasses L2 write-combining,
// and exact-capacity persistent grids can't self-balance across CUs.
// R3: non-persistent 8192-block grid, 4 block-strided items/thread (loads
// issued 4-deep for MLP), plain stores. Block covers 1024 consecutive float4
// = half a row → channel is block-uniform, weights hoisted once.

constexpr int C  = 128;
constexpr int L  = 8192;
constexpr int L4 = L / 4;          // 2048 float4 per row
constexpr int B  = 32;
constexpr int TOTAL4 = B * C * L4; // 8,388,608

constexpr int BLOCK = 256;
constexpr int BATCH = 4;                         // items per thread, block-strided
constexpr int ITEMS_PER_BLOCK = BLOCK * BATCH;   // 1024 float4 = half a row
constexpr int GRID  = TOTAL4 / ITEMS_PER_BLOCK;  // 8192, exact

static_assert(TOTAL4 % ITEMS_PER_BLOCK == 0, "exact tiling");
static_assert(L4 % ITEMS_PER_BLOCK == 0, "block never spans a row boundary");

__global__ __launch_bounds__(BLOCK) void dwconv1d_kernel(
    const float4* __restrict__ x4,
    const float* __restrict__ x,      // scalar view of same buffer (edge halos)
    const float* __restrict__ w,      // [C,3]
    const float* __restrict__ bias,   // [C]
    float4* __restrict__ out4)
{
    const int tid  = threadIdx.x;
    const int lane = tid & 63;
    const int idx0 = blockIdx.x * ITEMS_PER_BLOCK + tid;

    // Block covers [blockIdx*1024, blockIdx*1024+1024) → never crosses a
    // 2048-float4 row boundary → channel is block-uniform: scalar path.
    const int c = __builtin_amdgcn_readfirstlane((idx0 >> 11) & (C - 1));
    const float w0 = w[c * 3 + 0];
    const float w1 = w[c * 3 + 1];
    const float w2 = w[c * 3 + 2];
    const float bc = bias[c];

    const bool lane0  = (lane == 0);
    const bool lane63 = (lane == 63);

    // Issue all 4 loads before any use → 4 outstanding global_load_dwordx4.
    float4 v[BATCH];
    #pragma unroll
    for (int ji = 0; ji < BATCH; ++ji)
        v[ji] = x4[idx0 + ji * BLOCK];

    #pragma unroll
    for (int ji = 0; ji < BATCH; ++ji) {
        const int idx = idx0 + ji * BLOCK;
        const int i4  = idx & (L4 - 1);       // position within row
        const float4 vv = v[ji];

        // Halo from neighbor lanes (wave = 64 lanes on CDNA).
        float left  = __shfl_up(vv.w, 1);     // lane i gets lane i-1's v.w
        float right = __shfl_down(vv.x, 1);   // lane i gets lane i+1's v.x

        // Wave-edge lanes fetch across the wave boundary (or 0 at row edges).
        // i4==0 implies lane==0; i4==L4-1 implies lane==63.
        const long base = (long)idx * 4;
        if (lane0)  left  = (i4 == 0)      ? 0.0f : x[base - 1];
        if (lane63) right = (i4 == L4 - 1) ? 0.0f : x[base + 4];

        float4 o;
        o.x = fmaf(w0, left,  fmaf(w1, vv.x, fmaf(w2, vv.y, bc)));
        o.y = fmaf(w0, vv.x,  fmaf(w1, vv.y, fmaf(w2, vv.z, bc)));
        o.z = fmaf(w0, vv.y,  fmaf(w1, vv.z, fmaf(w2, vv.w, bc)));
        o.w = fmaf(w0, vv.z,  fmaf(w1, vv.w, fmaf(w2, right, bc)));

        out4[idx] = o;
    }
}

extern "C" void kernel_launch(void* const* d_in, const int* in_sizes, int n_in,
                              void* d_out, int out_size, void* d_ws, size_t ws_size,
                              hipStream_t stream)
{
    const float* x    = (const float*)d_in[0];  // [B,C,L]
    const float* w    = (const float*)d_in[1];  // [C,3]
    const float* bias = (const float*)d_in[2];  // [C]
    float* out        = (float*)d_out;

    dwconv1d_kernel<<<GRID, BLOCK, 0, stream>>>(
        (const float4*)x, x, w, bias, (float4*)out);
}

// Round 4
// 229.425 us; speedup vs baseline: 1.0333x; 1.0161x over previous
//
#include <hip/hip_runtime.h>

// Depthwise Conv1d: B=32, C=128, L=8192, K=3, pad=1, fp32.
// out[b,c,l] = w[c,0]*x[b,c,l-1] + w[c,1]*x[b,c,l] + w[c,2]*x[b,c,l+1] + bias[c]
// Memory-bound: ideal traffic 128 MiB read + 128 MiB write → ~43 µs @ 6.3 TB/s.
//
// R2 post-mortem: nontemporal stores + persistent exact-capacity grid → 81 µs
// conv @2.6 TB/s (nt defeats L2 write-combining). R3 post-mortem: 4-deep
// block-strided batching neutral-to-negative; session fill noise ±2-4%.
//
// R4: wave-contiguous 2-deep batching. Each wave owns 128 contiguous float4
// (2 KiB): item A = base+lane, item B = base+64+lane. Both loads unit-stride
// per instruction (same perfect coalescing as 1-item/thread), issued together
// → 2 outstanding dwordx4/thread. The A|B seam halo comes from intra-wave
// broadcasts (readlane), so exec-masked scalar halo loads drop to 2 per pair.
// Wave spans 512 floats; row = 8192 floats → wave never crosses a row:
// channel is wave-uniform (weights via s_load path).

constexpr int C  = 128;
constexpr int L  = 8192;
constexpr int L4 = L / 4;          // 2048 float4 per row
constexpr int B  = 32;
constexpr int TOTAL4 = B * C * L4; // 8,388,608

constexpr int BLOCK = 256;                        // 4 waves
constexpr int PER_WAVE = 128;                     // float4 per wave (A + B)
constexpr int PER_BLOCK = 4 * PER_WAVE;           // 512 float4
constexpr int GRID  = TOTAL4 / PER_BLOCK;         // 16384, exact

static_assert(TOTAL4 % PER_BLOCK == 0, "exact tiling");
static_assert(L4 % PER_WAVE == 0, "wave never spans a row boundary");

__global__ __launch_bounds__(BLOCK) void dwconv1d_kernel(
    const float4* __restrict__ x4,
    const float* __restrict__ x,      // scalar view of same buffer (edge halos)
    const float* __restrict__ w,      // [C,3]
    const float* __restrict__ bias,   // [C]
    float4* __restrict__ out4)
{
    const int tid  = threadIdx.x;
    const int lane = tid & 63;
    const int gw   = blockIdx.x * 4 + (tid >> 6);  // global wave id
    const int base = gw * PER_WAVE;                // float4 units
    const int idxA = base + lane;
    const int idxB = base + 64 + lane;

    // Wave covers 512 consecutive floats within one row → channel uniform.
    const int c = __builtin_amdgcn_readfirstlane((idxA >> 11) & (C - 1));
    const float w0 = w[c * 3 + 0];
    const float w1 = w[c * 3 + 1];
    const float w2 = w[c * 3 + 2];
    const float bc = bias[c];

    const bool lane0  = (lane == 0);
    const bool lane63 = (lane == 63);
    const bool rowstart = ((idxA & (L4 - 1)) == 0);        // implies lane==0
    const bool rowend   = ((idxB & (L4 - 1)) == L4 - 1);   // implies lane==63

    // Issue both loads before any use → 2 outstanding global_load_dwordx4.
    const float4 va = x4[idxA];
    const float4 vb = x4[idxB];

    // Neighbor-lane halos (wave = 64 lanes on CDNA).
    float leftA  = __shfl_up(va.w, 1);
    float rightA = __shfl_down(va.x, 1);
    float leftB  = __shfl_up(vb.w, 1);
    float rightB = __shfl_down(vb.x, 1);

    // A|B seam: lane63's rightA = lane0's vb.x; lane0's leftB = lane63's va.w.
    const float bx0  = __shfl(vb.x, 0);    // readlane broadcast
    const float aw63 = __shfl(va.w, 63);

    if (lane0)  leftA  = rowstart ? 0.0f : x[(long)idxA * 4 - 1];
    if (lane63) rightA = bx0;
    if (lane0)  leftB  = aw63;
    if (lane63) rightB = rowend ? 0.0f : x[(long)idxB * 4 + 4];

    float4 oa, ob;
    oa.x = fmaf(w0, leftA, fmaf(w1, va.x, fmaf(w2, va.y, bc)));
    oa.y = fmaf(w0, va.x,  fmaf(w1, va.y, fmaf(w2, va.z, bc)));
    oa.z = fmaf(w0, va.y,  fmaf(w1, va.z, fmaf(w2, va.w, bc)));
    oa.w = fmaf(w0, va.z,  fmaf(w1, va.w, fmaf(w2, rightA, bc)));

    ob.x = fmaf(w0, leftB, fmaf(w1, vb.x, fmaf(w2, vb.y, bc)));
    ob.y = fmaf(w0, vb.x,  fmaf(w1, vb.y, fmaf(w2, vb.z, bc)));
    ob.z = fmaf(w0, vb.y,  fmaf(w1, vb.z, fmaf(w2, vb.w, bc)));
    ob.w = fmaf(w0, vb.z,  fmaf(w1, vb.w, fmaf(w2, rightB, bc)));

    out4[idxA] = oa;
    out4[idxB] = ob;
}

extern "C" void kernel_launch(void* const* d_in, const int* in_sizes, int n_in,
                              void* d_out, int out_size, void* d_ws, size_t ws_size,
                              hipStream_t stream)
{
    const float* x    = (const float*)d_in[0];  // [B,C,L]
    const float* w    = (const float*)d_in[1];  // [C,3]
    const float* bias = (const float*)d_in[2];  // [C]
    float* out        = (float*)d_out;

    dwconv1d_kernel<<<GRID, BLOCK, 0, stream>>>(
        (const float4*)x, x, w, bias, (float4*)out);
}

// Round 5
// 223.520 us; speedup vs baseline: 1.0606x; 1.0264x over previous
//
#include <hip/hip_runtime.h>

// Depthwise Conv1d: B=32, C=128, L=8192, K=3, pad=1, fp32.
// out[b,c,l] = w[c,0]*x[b,c,l-1] + w[c,1]*x[b,c,l] + w[c,2]*x[b,c,l+1] + bias[c]
// Memory-bound: ideal traffic 128 MiB read + 128 MiB write → ~43 µs @ 6.3 TB/s.
//
// Session ledger:
//   R2: nontemporal stores + persistent grid → conv 81-85 µs @2.6 TB/s (BAD).
//   R0/R3/R4: 1/4/2-deep batching all ≈ conv 70-74 µs → MLP depth not the lever.
//   R5 (this): remove ALL cross-lane ops from the load→store critical path.
//
// Previous versions fetched halos via __shfl (ds_bpermute → lgkmcnt waits) +
// exec-masked lane-0/63 scalar loads. A pure copy (6.29 TB/s µbench) waits on
// vmcnt only. Here halos are loaded directly: left = x4[idx-1].w and
// right = x4[idx+1].x as two dword loads — same cache lines the neighboring
// waves' dwordx4 loads fetch anyway → L1/L2 hits, no extra HBM traffic, and
// the kernel becomes load×3 → fma → store with no lgkmcnt dependency at all.
// Row-boundary zeros: per-lane predicated selects (1 diverging lane / 2048).

constexpr int C  = 128;
constexpr int L  = 8192;
constexpr int L4 = L / 4;          // 2048 float4 per row
constexpr int B  = 32;
constexpr int TOTAL4 = B * C * L4; // 8,388,608 (exact multiple of 256)

constexpr int BLOCK = 256;
constexpr int GRID  = TOTAL4 / BLOCK;   // 32768, exact — R0's proven config

__global__ __launch_bounds__(BLOCK) void dwconv1d_kernel(
    const float4* __restrict__ x4,
    const float* __restrict__ x,      // scalar view of same buffer (halos)
    const float* __restrict__ w,      // [C,3]
    const float* __restrict__ bias,   // [C]
    float4* __restrict__ out4)
{
    const int idx = blockIdx.x * BLOCK + threadIdx.x;
    const int i4  = idx & (L4 - 1);        // position within row (float4 units)

    // Channel is wave-uniform (wave spans 256 floats; row = 8192) → s_load.
    const int c = __builtin_amdgcn_readfirstlane((idx >> 11) & (C - 1));
    const float w0 = w[c * 3 + 0];
    const float w1 = w[c * 3 + 1];
    const float w2 = w[c * 3 + 2];
    const float bc = bias[c];

    // Issue all loads up front; no cross-lane ops anywhere.
    const long  sbase = (long)idx * 4;
    const float4 v = x4[idx];
    const float left  = (i4 == 0)      ? 0.0f : x[sbase - 1];  // x4[idx-1].w
    const float right = (i4 == L4 - 1) ? 0.0f : x[sbase + 4];  // x4[idx+1].x

    float4 o;
    o.x = fmaf(w0, left, fmaf(w1, v.x, fmaf(w2, v.y, bc)));
    o.y = fmaf(w0, v.x,  fmaf(w1, v.y, fmaf(w2, v.z, bc)));
    o.z = fmaf(w0, v.y,  fmaf(w1, v.z, fmaf(w2, v.w, bc)));
    o.w = fmaf(w0, v.z,  fmaf(w1, v.w, fmaf(w2, right, bc)));

    out4[idx] = o;
}

extern "C" void kernel_launch(void* const* d_in, const int* in_sizes, int n_in,
                              void* d_out, int out_size, void* d_ws, size_t ws_size,
                              hipStream_t stream)
{
    const float* x    = (const float*)d_in[0];  // [B,C,L]
    const float* w    = (const float*)d_in[1];  // [C,3]
    const float* bias = (const float*)d_in[2];  // [C]
    float* out        = (float*)d_out;

    dwconv1d_kernel<<<GRID, BLOCK, 0, stream>>>(
        (const float4*)x, x, w, bias, (float4*)out);
}